// Round 14
// baseline (110.294 us; speedup 1.0000x reference)
//
#include <hip/hip_runtime.h>

#define N_W   8192
#define N_E   32
#define N_NUC 8
#define D_H   32
#define NTAB  2048
#define TAB_INVH 128.0f    // table step = 1/128, range [0, 16)
#define TAB_H    (1.0f/128.0f)
#define WPB   8            // walkers per block; wave = 2 walkers (lanes 0-31 / 32-63)
#define NBLK  (N_W / WPB)  // 1024 blocks; each builds table entries 2b, 2b+1

// ws layout (float units):
// [0, 8192)      float4 nodes[2048]: (v25_i, v25_{i+1}, v50_i, v50_{i+1})
//                vA(r) = A*cusp(r) + mlp(r). ONE 16B store per node, single writer.
// [8192, 8208)   aux: [0..7] sp(b_en), [8] sp(b_ee), [9] 32*scale_en*b3_en
// [8208, 8224)   masks: 16 u32, bit e of masks[d-1] = spin_parallel(e,(e+d)&31)
// [8224, 8256)   W3*scale_en [32]
// [8256, 8512)   W1T bf16 A-fragments (256 u32): rows=hidden j, k=nuc 0..7, k8=b1
// [8512, 9024)   W2T bf16 A-fragments (512 u32): rows=out j', k=hidden 0..31
// [9216]         u32 completion counter (64B-aligned, reset by memset node each call)
#define AUX_OFF 8192
#define MSK_OFF 8208
#define W3S_OFF 8224
#define W1T_OFF 8256
#define W2T_OFF 8512
#define CNT_OFF 9216

typedef __attribute__((ext_vector_type(8)))  short bf16x8_t;   // 8 bf16 = 4 VGPR
typedef __attribute__((ext_vector_type(16))) float f32x16_t;   // MFMA accumulator

union FragAB { bf16x8_t s; unsigned u[4]; };

__device__ __forceinline__ float fast_rcp(float x) { return __builtin_amdgcn_rcpf(x); }
__device__ __forceinline__ float silu_f(float v)   { return v * fast_rcp(1.0f + __expf(-v)); }
__device__ __forceinline__ unsigned pk_bf16(float lo, float hi) {
    unsigned r;
    asm("v_cvt_pk_bf16_f32 %0, %1, %2" : "=v"(r) : "v"(lo), "v"(hi));
    return r;
}

// ---------------- Fused kernel: build (phase 1) + spin-sync + walkers (phase 2) ----------
// All 1024 blocks are co-resident (zero LDS, VGPR<=128, 4 blocks/CU), and every block
// increments the counter BEFORE spinning, so builders never wait on spinners -> no
// deadlock. Table values are a pure function of inputs -> deterministic across replays.
__launch_bounds__(256, 4)
__global__ void fused_jastrow(const float* __restrict__ re, const float* __restrict__ rnuc,
                              const float* __restrict__ charges, const int* __restrict__ mask,
                              const float* __restrict__ b_en, const float* __restrict__ b_ee,
                              const float* __restrict__ W1ee, const float* __restrict__ b1ee,
                              const float* __restrict__ W2ee, const float* __restrict__ b2ee,
                              const float* __restrict__ W3ee, const float* __restrict__ b3ee,
                              const float* __restrict__ scale_ee,
                              const float* __restrict__ W1en, const float* __restrict__ b1en,
                              const float* __restrict__ W2en, const float* __restrict__ b2en,
                              const float* __restrict__ W3en, const float* __restrict__ b3en,
                              const float* __restrict__ scale_en,
                              float* ws, float* __restrict__ out)
{
    const int tid = threadIdx.x;

    // Issue own-coords loads early (HBM latency hides under build+sync)
    const int e    = tid & 31;
    const int w    = blockIdx.x * WPB + (tid >> 5);
    const float* cb = re + ((size_t)w * N_E + e) * 3;
    float ex = cb[0], ey = cb[1], ez = cb[2];

    // ================= Phase 1: build =================
    if (tid < 128) {   // groups 0,1: table entries 2b+0, 2b+1 (R13 node math)
        const int entry = blockIdx.x * 2 + (tid >> 6);
        const int j = tid & 31, kh = (tid >> 5) & 1;
        float mlp[2];
#pragma unroll
        for (int t = 0; t < 2; ++t) {
            float r = ((float)entry + (float)t) * TAB_H;
            float g = kh ? 0.0f : b2ee[j];
#pragma unroll
            for (int kk = 0; kk < 16; ++kk) {
                int k = kh * 16 + kk;
                g += silu_f(r * W1ee[k] + b1ee[k]) * W2ee[k * D_H + j];
            }
            g += __shfl_xor(g, 32, 64);
            float o = silu_f(g) * W3ee[j];
#pragma unroll
            for (int m = 16; m; m >>= 1) o += __shfl_xor(o, m, 32);
            mlp[t] = o;
        }
        if ((tid & 63) == 0) {
            float bs = __logf(1.0f + __expf(b_ee[0]));
            float r0 = (float)entry * TAB_H, r1 = r0 + TAB_H;
            float c0 = r0 * fast_rcp(1.0f + bs * r0);
            float c1 = r1 * fast_rcp(1.0f + bs * r1);
            float m0 = scale_ee[0] * (mlp[0] + b3ee[0]);
            float m1 = scale_ee[0] * (mlp[1] + b3ee[0]);
            *(float4*)(ws + (entry << 2)) =
                make_float4(fmaf(0.25f, c0, m0), fmaf(0.25f, c1, m1),
                            fmaf(0.50f, c0, m0), fmaf(0.50f, c1, m1));
        }
    }
    if (blockIdx.x == 0) {
        float* auxw = ws + AUX_OFF;
        if (tid < N_NUC) auxw[tid] = __logf(1.0f + __expf(b_en[tid]));
        if (tid == 8)    auxw[8]   = __logf(1.0f + __expf(b_ee[0]));
        if (tid == 9)    auxw[9]   = 32.0f * scale_en[0] * b3en[0];
        if (tid >= 32 && tid < 64) ws[W3S_OFF + tid - 32] = W3en[tid - 32] * scale_en[0];
        if (tid >= 64 && tid < 80) {       // spin masks, d = tid-63
            int d = tid - 63;
            unsigned m = 0;
            for (int e2 = 0; e2 < N_E; ++e2) {
                int jn = (e2 + d) & 31;
                int a = e2 < jn ? e2 : jn, b = e2 < jn ? jn : e2;
                if (mask[a * N_E + b]) m |= (1u << e2);
            }
            ((unsigned*)(ws + MSK_OFF))[d - 1] = m;
        }
        {   // W1T A-fragments
            int L = tid >> 2, r = tid & 3, j = L & 31;
            unsigned u = 0;
            if (L < 32)      u = pk_bf16(W1en[(2 * r) * D_H + j], W1en[(2 * r + 1) * D_H + j]);
            else if (r == 0) u = pk_bf16(b1en[j], 0.0f);
            ((unsigned*)(ws + W1T_OFF))[(L << 2) + r] = u;
        }
#pragma unroll
        for (int q = 0; q < 2; ++q) {      // W2T A-fragments (512 u32)
            int idx = tid + (q << 8);
            int L = idx >> 3, s = idx & 7, j = L & 31;
            int kb = ((L >> 5) << 3) + ((s & 3) << 1) + ((s >> 2) << 4);
            ((unsigned*)(ws + W2T_OFF))[(L << 3) + s] =
                pk_bf16(W2en[kb * D_H + j], W2en[(kb + 1) * D_H + j]);
        }
    }

    // ================= Spin-sync (increment-then-wait; all blocks resident) ==========
    {
        unsigned* cnt = (unsigned*)(ws + CNT_OFF);
        __syncthreads();
        if (tid == 0) {
            __threadfence();                       // device-scope release of our stores
            atomicAdd(cnt, 1u);                    // device-scope by default
            while (__hip_atomic_load(cnt, __ATOMIC_ACQUIRE,
                                     __HIP_MEMORY_SCOPE_AGENT) < (unsigned)NBLK)
                __builtin_amdgcn_s_sleep(2);
            __threadfence();                       // acquire side
        }
        __syncthreads();
    }

    // ================= Phase 2: walkers (R13 body) =================
    const int lane = tid & 63;
    const bool lo  = (tid & 32) == 0;
    const float* aux = ws + AUX_OFF;

    float acc = 0.0f;

    // ---- e-n cusp + r^2 ----
    float x[N_NUC];
#pragma unroll
    for (int n = 0; n < N_NUC; ++n) {
        float dx = ex - rnuc[n * 3 + 0];
        float dy = ey - rnuc[n * 3 + 1];
        float dz = ez - rnuc[n * 3 + 2];
        float r2 = dx * dx + dy * dy + dz * dz;
        x[n] = r2;
        float r = sqrtf(r2);
        acc -= charges[n] * r * fast_rcp(1.0f + aux[n] * r);
    }

    // ---- pack x to bf16; exchange across halves for walker-B's MFMA ----
    unsigned xpk[4], sxp[4];
#pragma unroll
    for (int r = 0; r < 4; ++r) xpk[r] = pk_bf16(x[2 * r], x[2 * r + 1]);
#pragma unroll
    for (int r = 0; r < 4; ++r) sxp[r] = (unsigned)__shfl_xor((int)xpk[r], 32, 64);

    FragAB B1A, B1B;
#pragma unroll
    for (int r = 0; r < 4; ++r) {
        unsigned oneh = (r == 0) ? 0x00003F80u : 0u;   // bf16 (1.0, 0.0)
        B1A.u[r] = lo ? xpk[r] : oneh;
        B1B.u[r] = lo ? sxp[r] : oneh;
    }
    FragAB A1;
    {
        uint4 q = *((const uint4*)((const unsigned*)(ws + W1T_OFF) + (lane << 2)));
        A1.u[0] = q.x; A1.u[1] = q.y; A1.u[2] = q.z; A1.u[3] = q.w;
    }
    f32x16_t z;
#pragma unroll
    for (int r = 0; r < 16; ++r) z[r] = 0.0f;
    f32x16_t HA = __builtin_amdgcn_mfma_f32_32x32x16_bf16(A1.s, B1A.s, z, 0, 0, 0);
    f32x16_t HB = __builtin_amdgcn_mfma_f32_32x32x16_bf16(A1.s, B1B.s, z, 0, 0, 0);

    FragAB A2a, A2b;
    {
        const unsigned* p = (const unsigned*)(ws + W2T_OFF) + ((size_t)lane << 3);
        uint4 q0 = *(const uint4*)p;
        uint4 q1 = *(const uint4*)(p + 4);
        A2a.u[0] = q0.x; A2a.u[1] = q0.y; A2a.u[2] = q0.z; A2a.u[3] = q0.w;
        A2b.u[0] = q1.x; A2b.u[1] = q1.y; A2b.u[2] = q1.z; A2b.u[3] = q1.w;
    }
    float b2v[16], w3v[16];
    {
        const int base = ((lane >> 5) << 2);           // +4 if hi half
#pragma unroll
        for (int rq = 0; rq < 4; ++rq) {               // rows 8*rq + base + 0..3
            float4 cb2 = *(const float4*)(b2en + (rq << 3) + base);
            float4 cw3 = *(const float4*)(ws + W3S_OFF + (rq << 3) + base);
            b2v[4 * rq + 0] = cb2.x; b2v[4 * rq + 1] = cb2.y;
            b2v[4 * rq + 2] = cb2.z; b2v[4 * rq + 3] = cb2.w;
            w3v[4 * rq + 0] = cw3.x; w3v[4 * rq + 1] = cw3.y;
            w3v[4 * rq + 2] = cw3.z; w3v[4 * rq + 3] = cw3.w;
        }
    }

    float sA, sB;
#pragma unroll
    for (int wk = 0; wk < 2; ++wk) {                   // walker A then B
        const f32x16_t& H = wk ? HB : HA;
        unsigned p[8], sx2[8];
#pragma unroll
        for (int i = 0; i < 8; ++i)
            p[i] = pk_bf16(silu_f(H[2 * i]), silu_f(H[2 * i + 1]));
#pragma unroll
        for (int i = 0; i < 8; ++i) sx2[i] = (unsigned)__shfl_xor((int)p[i], 32, 64);
        FragAB Ba, Bb;
        Ba.u[0] = lo ? p[0]   : sx2[2];
        Ba.u[1] = lo ? p[1]   : sx2[3];
        Ba.u[2] = lo ? sx2[0] : p[2];
        Ba.u[3] = lo ? sx2[1] : p[3];
        Bb.u[0] = lo ? p[4]   : sx2[6];
        Bb.u[1] = lo ? p[5]   : sx2[7];
        Bb.u[2] = lo ? sx2[4] : p[6];
        Bb.u[3] = lo ? sx2[5] : p[7];
        f32x16_t g;
#pragma unroll
        for (int r = 0; r < 16; ++r) g[r] = b2v[r];
        g = __builtin_amdgcn_mfma_f32_32x32x16_bf16(A2a.s, Ba.s, g, 0, 0, 0);
        g = __builtin_amdgcn_mfma_f32_32x32x16_bf16(A2b.s, Bb.s, g, 0, 0, 0);
        float s = 0.0f;
#pragma unroll
        for (int r = 0; r < 16; ++r) s += silu_f(g[r]) * w3v[r];
        if (wk == 0) sA = s; else sB = s;
    }

    // ---- e-e: rotation pairs; ONE 16B node load per pair + spin cndmask + lerp ----
    unsigned mks[16];
    {
        const unsigned* mp = (const unsigned*)(ws + MSK_OFF);
#pragma unroll
        for (int i = 0; i < 16; ++i) mks[i] = mp[i];
    }
    const float4* tb = (const float4*)ws;
#pragma unroll
    for (int d = 1; d <= 16; ++d) {
        int jn = (e + d) & 31;
        float cjx = __shfl(ex, jn, 32);
        float cjy = __shfl(ey, jn, 32);
        float cjz = __shfl(ez, jn, 32);
        float dx = ex - cjx, dy = ey - cjy, dz = ez - cjz;
        float r = sqrtf(dx * dx + dy * dy + dz * dz);
        float t = r * TAB_INVH;
        int i0 = (int)t;
        if (i0 > NTAB - 2) i0 = NTAB - 2;
        float f = t - (float)i0;
        float4 nd = tb[i0];                            // (v25_i, v25_i1, v50_i, v50_i1)
        bool par = (mks[d - 1] >> e) & 1u;             // parallel -> 0.25 variant
        float v0 = par ? nd.x : nd.z;
        float v1 = par ? nd.y : nd.w;
        float pv = fmaf(f, v1 - v0, v0);
        acc += (d == 16) ? 0.5f * pv : pv;             // d=16 pairs counted twice
    }

    // ---- per-walker totals; 64-lane reduce; write 2 walkers ----
    float valA = sA + (lo ? acc : 0.0f);
    float valB = sB + (lo ? 0.0f : acc);
#pragma unroll
    for (int m = 32; m; m >>= 1) {
        valA += __shfl_xor(valA, m, 64);
        valB += __shfl_xor(valB, m, 64);
    }
    if ((tid & 63) == 0) {
        int wA = blockIdx.x * WPB + ((tid >> 6) << 1);
        out[wA]     = valA + aux[9];
        out[wA + 1] = valB + aux[9];
    }
}

extern "C" void kernel_launch(void* const* d_in, const int* in_sizes, int n_in,
                              void* d_out, int out_size, void* d_ws, size_t ws_size,
                              hipStream_t stream)
{
    const float* re       = (const float*)d_in[0];
    const float* rnuc     = (const float*)d_in[1];
    const float* charges  = (const float*)d_in[2];
    const int*   mask     = (const int*)d_in[3];
    const float* b_en     = (const float*)d_in[4];
    const float* b_ee     = (const float*)d_in[5];
    const float* W1_en    = (const float*)d_in[6];
    const float* b1_en    = (const float*)d_in[7];
    const float* W2_en    = (const float*)d_in[8];
    const float* b2_en    = (const float*)d_in[9];
    const float* W3_en    = (const float*)d_in[10];
    const float* b3_en    = (const float*)d_in[11];
    const float* W1_ee    = (const float*)d_in[12];
    const float* b1_ee    = (const float*)d_in[13];
    const float* W2_ee    = (const float*)d_in[14];
    const float* b2_ee    = (const float*)d_in[15];
    const float* W3_ee    = (const float*)d_in[16];
    const float* b3_ee    = (const float*)d_in[17];
    const float* scale_en = (const float*)d_in[18];
    const float* scale_ee = (const float*)d_in[19];

    float* out = (float*)d_out;
    float* ws  = (float*)d_ws;

    // reset the sync counter each call (graph-legal memset node)
    hipMemsetAsync((void*)(ws + CNT_OFF), 0, sizeof(unsigned), stream);

    fused_jastrow<<<NBLK, 256, 0, stream>>>(re, rnuc, charges, mask, b_en, b_ee,
                                            W1_ee, b1_ee, W2_ee, b2_ee, W3_ee, b3_ee,
                                            scale_ee,
                                            W1_en, b1_en, W2_en, b2_en, W3_en, b3_en,
                                            scale_en, ws, out);
}

// Round 15
// 20.634 us; speedup vs baseline: 5.3452x; 5.3452x over previous
//
#include <hip/hip_runtime.h>

#define N_W   8192
#define N_E   32
#define N_NUC 8
#define D_H   32
#define NTAB  2048
#define TAB_INVH 128.0f    // table step = 1/128, range [0, 16)
#define TAB_H    (1.0f/128.0f)
#define WPB   8            // walkers per block; wave = 2 walkers (lanes 0-31 / 32-63)

// ws layout (float units):
// [0, 4096)      T0: 2048 float2 nodes (v25_i, v25_{i+1});  vA(r)=A*cusp(r)+mlp(r)
// [4096, 8192)   T1: 2048 float2 nodes (v50_i, v50_{i+1})
//                block b owns entries 4b..4b+3 of each table = 32B-aligned chunk,
//                written only by block b (no cross-XCD partial-line writes).
// [8192, 8208)   aux: [0..7] sp(b_en), [8] sp(b_ee), [9] 32*scale_en*b3_en
// [8208, 8224)   masks: 16 u32, bit e of masks[d-1] = spin_parallel(e,(e+d)&31)
// [8224, 8256)   W3*scale_en [32]
// [8256, 8512)   W1T bf16 A-fragments (256 u32): rows=hidden j, k=nuc 0..7, k8=b1
// [8512, 9024)   W2T bf16 A-fragments (512 u32): rows=out j', k=hidden 0..31
#define T1_OFF  4096
#define AUX_OFF 8192
#define MSK_OFF 8208
#define W3S_OFF 8224
#define W1T_OFF 8256
#define W2T_OFF 8512

typedef __attribute__((ext_vector_type(8)))  short bf16x8_t;   // 8 bf16 = 4 VGPR
typedef __attribute__((ext_vector_type(16))) float f32x16_t;   // MFMA accumulator

union FragAB { bf16x8_t s; unsigned u[4]; };

__device__ __forceinline__ float fast_rcp(float x) { return __builtin_amdgcn_rcpf(x); }
__device__ __forceinline__ float silu_f(float v)   { return v * fast_rcp(1.0f + __expf(-v)); }
__device__ __forceinline__ unsigned pk_bf16(float lo, float hi) {
    unsigned r;
    asm("v_cvt_pk_bf16_f32 %0, %1, %2" : "=v"(r) : "v"(lo), "v"(hi));
    return r;
}

// ---------------- Pre-kernel: two spin-baked float2 tables + aux + masks + W1T/W2T ------
// 512 blocks x 256. One table entry per 64-lane group (lane j = hidden unit, k-half
// (tid>>5)&1; shfl_xor(32) combines). Group evaluates the ee-MLP at r_i AND r_{i+1};
// lane 0 writes one float2 node per table. Block b's nodes = entries 4b..4b+3.
__global__ void build_tables(const float* __restrict__ W1ee, const float* __restrict__ b1ee,
                             const float* __restrict__ W2ee, const float* __restrict__ b2ee,
                             const float* __restrict__ W3ee, const float* __restrict__ b3ee,
                             const float* __restrict__ scale_ee,
                             const float* __restrict__ b_en, const float* __restrict__ b_ee,
                             const int* __restrict__ mask,
                             const float* __restrict__ W1en, const float* __restrict__ b1en,
                             const float* __restrict__ W2en, const float* __restrict__ W3en,
                             const float* __restrict__ b3en, const float* __restrict__ scale_en,
                             float* __restrict__ ws)
{
    const int tid = threadIdx.x;
    if (blockIdx.x == 0) {
        float* aux = ws + AUX_OFF;
        if (tid < N_NUC) aux[tid] = __logf(1.0f + __expf(b_en[tid]));
        if (tid == 8)    aux[8]   = __logf(1.0f + __expf(b_ee[0]));
        if (tid == 9)    aux[9]   = 32.0f * scale_en[0] * b3en[0];
        if (tid >= 32 && tid < 64) ws[W3S_OFF + tid - 32] = W3en[tid - 32] * scale_en[0];
        if (tid >= 64 && tid < 80) {       // spin masks, d = tid-63
            int d = tid - 63;
            unsigned m = 0;
            for (int e2 = 0; e2 < N_E; ++e2) {
                int jn = (e2 + d) & 31;
                int a = e2 < jn ? e2 : jn, b = e2 < jn ? jn : e2;
                if (mask[a * N_E + b]) m |= (1u << e2);
            }
            ((unsigned*)(ws + MSK_OFF))[d - 1] = m;
        }
        {   // W1T A-fragments: lane L row j=L&31; lo lanes k0..7 = W1[k][j]; hi: k8=b1[j]
            int L = tid >> 2, r = tid & 3, j = L & 31;
            unsigned u = 0;
            if (L < 32)      u = pk_bf16(W1en[(2 * r) * D_H + j], W1en[(2 * r + 1) * D_H + j]);
            else if (r == 0) u = pk_bf16(b1en[j], 0.0f);
            ((unsigned*)(ws + W1T_OFF))[(L << 2) + r] = u;
        }
#pragma unroll
        for (int q = 0; q < 2; ++q) {      // W2T A-fragments (512 u32)
            int idx = tid + (q << 8);
            int L = idx >> 3, s = idx & 7, j = L & 31;
            int kb = ((L >> 5) << 3) + ((s & 3) << 1) + ((s >> 2) << 4);
            ((unsigned*)(ws + W2T_OFF))[(L << 3) + s] =
                pk_bf16(W2en[kb * D_H + j], W2en[(kb + 1) * D_H + j]);
        }
    }
    // ---- ee node: MLP + cusp at r_i and r_{i+1}, spin variants baked ----
    const int entry = blockIdx.x * 4 + (tid >> 6);
    const int j = tid & 31, kh = (tid >> 5) & 1;
    float mlp[2];
#pragma unroll
    for (int t = 0; t < 2; ++t) {
        float r = ((float)entry + (float)t) * TAB_H;
        float g = kh ? 0.0f : b2ee[j];
#pragma unroll
        for (int kk = 0; kk < 16; ++kk) {
            int k = kh * 16 + kk;
            g += silu_f(r * W1ee[k] + b1ee[k]) * W2ee[k * D_H + j];
        }
        g += __shfl_xor(g, 32, 64);
        float o = silu_f(g) * W3ee[j];
#pragma unroll
        for (int m = 16; m; m >>= 1) o += __shfl_xor(o, m, 32);
        mlp[t] = o;
    }
    if ((tid & 63) == 0) {
        float bs = __logf(1.0f + __expf(b_ee[0]));
        float r0 = (float)entry * TAB_H, r1 = r0 + TAB_H;
        float c0 = r0 * fast_rcp(1.0f + bs * r0);
        float c1 = r1 * fast_rcp(1.0f + bs * r1);
        float m0 = scale_ee[0] * (mlp[0] + b3ee[0]);
        float m1 = scale_ee[0] * (mlp[1] + b3ee[0]);
        *(float2*)(ws + (entry << 1)) =
            make_float2(fmaf(0.25f, c0, m0), fmaf(0.25f, c1, m1));
        *(float2*)(ws + T1_OFF + (entry << 1)) =
            make_float2(fmaf(0.50f, c0, m0), fmaf(0.50f, c1, m1));
    }
}

// ---------------- Main kernel (R13 math; e-e gathers issued EARLY, consumed late) -------
// Wave = 2 walkers. e-e: distances + addresses computed right after coords arrive;
// all 16 float2 gathers issued BEFORE the MLP so their L1/L2 latency hides under
// cusp + pack + layer-1 MFMA. Spin select folded into the gather address.
__launch_bounds__(256, 4)
__global__ void jastrow_kernel(const float* __restrict__ re, const float* __restrict__ rnuc,
                               const float* __restrict__ charges,
                               const float* __restrict__ b2,
                               const float* __restrict__ ws,
                               float* __restrict__ out)
{
    const int tid  = threadIdx.x;
    const int e    = tid & 31;          // electron
    const int lane = tid & 63;
    const bool lo  = (tid & 32) == 0;
    const int w    = blockIdx.x * WPB + (tid >> 5);
    const float* aux = ws + AUX_OFF;

    const float* cb = re + ((size_t)w * N_E + e) * 3;
    float ex = cb[0], ey = cb[1], ez = cb[2];

    // ---- e-e phase 1: distances, lerp fractions, ISSUE all 16 gathers ----
    unsigned mks[16];
    {
        const unsigned* mp = (const unsigned*)(ws + MSK_OFF);
#pragma unroll
        for (int i = 0; i < 16; ++i) mks[i] = mp[i];
    }
    float  f_[16];
    float2 nd[16];
#pragma unroll
    for (int d = 1; d <= 16; ++d) {
        int jn = (e + d) & 31;
        float cjx = __shfl(ex, jn, 32);
        float cjy = __shfl(ey, jn, 32);
        float cjz = __shfl(ez, jn, 32);
        float dx = ex - cjx, dy = ey - cjy, dz = ez - cjz;
        float r = sqrtf(dx * dx + dy * dy + dz * dz);
        float t = r * TAB_INVH;
        int i0 = (int)t;
        if (i0 > NTAB - 2) i0 = NTAB - 2;
        f_[d - 1] = t - (float)i0;
        bool par = (mks[d - 1] >> e) & 1u;             // parallel -> 0.25 table (T0)
        const float* np = ws + (par ? 0 : T1_OFF) + (i0 << 1);
        nd[d - 1] = *(const float2*)np;                // issued here, consumed later
    }

    float acc = 0.0f;

    // ---- e-n cusp + r^2 ----
    float x[N_NUC];
#pragma unroll
    for (int n = 0; n < N_NUC; ++n) {
        float dx = ex - rnuc[n * 3 + 0];
        float dy = ey - rnuc[n * 3 + 1];
        float dz = ez - rnuc[n * 3 + 2];
        float r2 = dx * dx + dy * dy + dz * dz;
        x[n] = r2;
        float r = sqrtf(r2);
        acc -= charges[n] * r * fast_rcp(1.0f + aux[n] * r);
    }

    // ---- pack x to bf16; exchange across halves for walker-B's MFMA ----
    unsigned xpk[4], sxp[4];
#pragma unroll
    for (int r = 0; r < 4; ++r) xpk[r] = pk_bf16(x[2 * r], x[2 * r + 1]);
#pragma unroll
    for (int r = 0; r < 4; ++r) sxp[r] = (unsigned)__shfl_xor((int)xpk[r], 32, 64);

    FragAB B1A, B1B;
#pragma unroll
    for (int r = 0; r < 4; ++r) {
        unsigned oneh = (r == 0) ? 0x00003F80u : 0u;   // bf16 (1.0, 0.0)
        B1A.u[r] = lo ? xpk[r] : oneh;
        B1B.u[r] = lo ? sxp[r] : oneh;
    }
    FragAB A1;
    {
        uint4 q = *((const uint4*)((const unsigned*)(ws + W1T_OFF) + (lane << 2)));
        A1.u[0] = q.x; A1.u[1] = q.y; A1.u[2] = q.z; A1.u[3] = q.w;
    }
    f32x16_t z;
#pragma unroll
    for (int r = 0; r < 16; ++r) z[r] = 0.0f;
    f32x16_t HA = __builtin_amdgcn_mfma_f32_32x32x16_bf16(A1.s, B1A.s, z, 0, 0, 0);
    f32x16_t HB = __builtin_amdgcn_mfma_f32_32x32x16_bf16(A1.s, B1B.s, z, 0, 0, 0);

    // ---- e-e phase 2: consume gathers (frees nd/f_ registers before layer 2) ----
#pragma unroll
    for (int d = 1; d <= 16; ++d) {
        float pv = fmaf(f_[d - 1], nd[d - 1].y - nd[d - 1].x, nd[d - 1].x);
        acc += (d == 16) ? 0.5f * pv : pv;             // d=16 pairs counted twice
    }

    // ---- layer-2 A operands (prepacked W2T) + row-indexed b2 / W3s (float4 loads) ----
    FragAB A2a, A2b;
    {
        const unsigned* p = (const unsigned*)(ws + W2T_OFF) + ((size_t)lane << 3);
        uint4 q0 = *(const uint4*)p;
        uint4 q1 = *(const uint4*)(p + 4);
        A2a.u[0] = q0.x; A2a.u[1] = q0.y; A2a.u[2] = q0.z; A2a.u[3] = q0.w;
        A2b.u[0] = q1.x; A2b.u[1] = q1.y; A2b.u[2] = q1.z; A2b.u[3] = q1.w;
    }
    float b2v[16], w3v[16];
    {
        const int base = ((lane >> 5) << 2);           // +4 if hi half
#pragma unroll
        for (int rq = 0; rq < 4; ++rq) {               // rows 8*rq + base + 0..3
            float4 cb2 = *(const float4*)(b2 + (rq << 3) + base);
            float4 cw3 = *(const float4*)(ws + W3S_OFF + (rq << 3) + base);
            b2v[4 * rq + 0] = cb2.x; b2v[4 * rq + 1] = cb2.y;
            b2v[4 * rq + 2] = cb2.z; b2v[4 * rq + 3] = cb2.w;
            w3v[4 * rq + 0] = cw3.x; w3v[4 * rq + 1] = cw3.y;
            w3v[4 * rq + 2] = cw3.z; w3v[4 * rq + 3] = cw3.w;
        }
    }

    float sA, sB;
#pragma unroll
    for (int wk = 0; wk < 2; ++wk) {                   // walker A then B
        const f32x16_t& H = wk ? HB : HA;
        unsigned p[8], sx2[8];
#pragma unroll
        for (int i = 0; i < 8; ++i)
            p[i] = pk_bf16(silu_f(H[2 * i]), silu_f(H[2 * i + 1]));
#pragma unroll
        for (int i = 0; i < 8; ++i) sx2[i] = (unsigned)__shfl_xor((int)p[i], 32, 64);
        FragAB Ba, Bb;
        Ba.u[0] = lo ? p[0]   : sx2[2];
        Ba.u[1] = lo ? p[1]   : sx2[3];
        Ba.u[2] = lo ? sx2[0] : p[2];
        Ba.u[3] = lo ? sx2[1] : p[3];
        Bb.u[0] = lo ? p[4]   : sx2[6];
        Bb.u[1] = lo ? p[5]   : sx2[7];
        Bb.u[2] = lo ? sx2[4] : p[6];
        Bb.u[3] = lo ? sx2[5] : p[7];
        f32x16_t g;
#pragma unroll
        for (int r = 0; r < 16; ++r) g[r] = b2v[r];
        g = __builtin_amdgcn_mfma_f32_32x32x16_bf16(A2a.s, Ba.s, g, 0, 0, 0);
        g = __builtin_amdgcn_mfma_f32_32x32x16_bf16(A2b.s, Bb.s, g, 0, 0, 0);
        float s = 0.0f;
#pragma unroll
        for (int r = 0; r < 16; ++r) s += silu_f(g[r]) * w3v[r];
        if (wk == 0) sA = s; else sB = s;
    }

    // ---- per-walker totals; 64-lane reduce; write 2 walkers ----
    float valA = sA + (lo ? acc : 0.0f);
    float valB = sB + (lo ? 0.0f : acc);
#pragma unroll
    for (int m = 32; m; m >>= 1) {
        valA += __shfl_xor(valA, m, 64);
        valB += __shfl_xor(valB, m, 64);
    }
    if ((tid & 63) == 0) {
        int wA = blockIdx.x * WPB + ((tid >> 6) << 1);
        out[wA]     = valA + aux[9];
        out[wA + 1] = valB + aux[9];
    }
}

extern "C" void kernel_launch(void* const* d_in, const int* in_sizes, int n_in,
                              void* d_out, int out_size, void* d_ws, size_t ws_size,
                              hipStream_t stream)
{
    const float* re       = (const float*)d_in[0];
    const float* rnuc     = (const float*)d_in[1];
    const float* charges  = (const float*)d_in[2];
    const int*   mask     = (const int*)d_in[3];
    const float* b_en     = (const float*)d_in[4];
    const float* b_ee     = (const float*)d_in[5];
    const float* W1_en    = (const float*)d_in[6];
    const float* b1_en    = (const float*)d_in[7];
    const float* W2_en    = (const float*)d_in[8];
    const float* b2_en    = (const float*)d_in[9];
    const float* W3_en    = (const float*)d_in[10];
    const float* b3_en    = (const float*)d_in[11];
    const float* W1_ee    = (const float*)d_in[12];
    const float* b1_ee    = (const float*)d_in[13];
    const float* W2_ee    = (const float*)d_in[14];
    const float* b2_ee    = (const float*)d_in[15];
    const float* W3_ee    = (const float*)d_in[16];
    const float* b3_ee    = (const float*)d_in[17];
    const float* scale_en = (const float*)d_in[18];
    const float* scale_ee = (const float*)d_in[19];

    float* out = (float*)d_out;
    float* ws  = (float*)d_ws;

    build_tables<<<NTAB / 4, 256, 0, stream>>>(W1_ee, b1_ee, W2_ee, b2_ee, W3_ee, b3_ee,
                                               scale_ee, b_en, b_ee, mask,
                                               W1_en, b1_en, W2_en, W3_en, b3_en, scale_en,
                                               ws);
    jastrow_kernel<<<N_W / WPB, 256, 0, stream>>>(re, rnuc, charges, b2_en, ws, out);
}